// Round 1
// baseline (695.145 us; speedup 1.0000x reference)
//
#include <hip/hip_runtime.h>

namespace {

constexpr int T = 2048;
constexpr int B = 8192;
constexpr int UNROLL = 8;

// One Izhikevich Euler step, bit-exact op order vs the JAX reference
// (no FMA contraction, left-associated sums, u-update before spike handling).
__device__ __forceinline__ float izh_step(float& v, float& u, float I) {
#pragma clang fp contract(off)
    float m2 = (0.04f * v) * v;       // (0.04*v)*v
    float s1 = m2 + (5.0f * v);
    float s2 = s1 + 140.0f;
    float s3 = s2 - u;
    float s4 = s3 + I;                // DT=1: v + 1.0*s4 == v + s4
    float vn = v + s4;
    float m4 = 0.2f * vn;             // B_P * v_new
    float s5 = m4 - u;
    float un = u + 0.02f * s5;        // DT*A == 0.02 exactly (1.0*0.02)
    bool  sp = (vn >= 30.0f);
    float z  = sp ? 1.0f : 0.0f;
    v = sp ? -65.0f : vn;             // where(z>0, C, v)
    u = un + z * 8.0f;                // u + z*D (z*8 exact)
    return z;
}

__global__ __launch_bounds__(64, 1) void izh_fused(
    const float* __restrict__ xs,
    const float* __restrict__ W_in, const float* __restrict__ b_in,
    const float* __restrict__ W_out, const float* __restrict__ b_out,
    float* __restrict__ out)
{
#pragma clang fp contract(off)
    const int b = blockIdx.x * 64 + threadIdx.x;   // one thread per batch element

    // Broadcast weights (L2-cached scalar-ish loads, once per thread).
    const float w00 = W_in[0], w01 = W_in[1], w02 = W_in[2], w03 = W_in[3];
    const float w10 = W_in[4], w11 = W_in[5], w12 = W_in[6], w13 = W_in[7];
    const float bi0 = b_in[0], bi1 = b_in[1];
    const float wo0 = W_out[0], wo1 = W_out[1];
    const float bo  = b_out[0];

    // States: v0 = C = -65, u0 = B_P*C = -13 (exact in f32).
    float v0 = -65.0f, u0 = -13.0f;   // hidden neuron 0
    float v1 = -65.0f, u1 = -13.0f;   // hidden neuron 1
    float vo = -65.0f, uo = -13.0f;   // output neuron

    const float4* xp = reinterpret_cast<const float4*>(xs) + b;  // [T][B] float4
    float* op = out + b;

    // Software pipeline: double register buffer, 8 float4 loads in flight
    // (HBM latency ~900 cyc vs ~200 cyc compute/step; depth-8 amortizes it).
    float4 bufA[UNROLL], bufB[UNROLL];
#pragma unroll
    for (int j = 0; j < UNROLL; ++j) bufA[j] = xp[(size_t)j * B];

    for (int tc = 0; tc < T; tc += UNROLL) {
        if (tc + UNROLL < T) {        // wave-uniform branch
#pragma unroll
            for (int j = 0; j < UNROLL; ++j)
                bufB[j] = xp[(size_t)(tc + UNROLL + j) * B];
        }
#pragma unroll
        for (int j = 0; j < UNROLL; ++j) {
            const float4 x = bufA[j];
            // h = x @ W_in^T + b_in, left-associated i=0..3 like XLA's small dot.
            float h0 = (((x.x * w00) + (x.y * w01)) + (x.z * w02)) + (x.w * w03);
            h0 = h0 + bi0;
            float h1 = (((x.x * w10) + (x.y * w11)) + (x.z * w12)) + (x.w * w13);
            h1 = h1 + bi1;
            float z0 = izh_step(v0, u0, h0);
            float z1 = izh_step(v1, u1, h1);
            float y  = ((z0 * wo0) + (z1 * wo1)) + bo;
            float zo = izh_step(vo, uo, y);
            op[(size_t)(tc + j) * B] = zo;
        }
#pragma unroll
        for (int j = 0; j < UNROLL; ++j) bufA[j] = bufB[j];
    }
}

} // namespace

extern "C" void kernel_launch(void* const* d_in, const int* in_sizes, int n_in,
                              void* d_out, int out_size, void* d_ws, size_t ws_size,
                              hipStream_t stream) {
    const float* xs    = (const float*)d_in[0];
    const float* W_in  = (const float*)d_in[1];
    const float* b_in  = (const float*)d_in[2];
    const float* W_out = (const float*)d_in[3];
    const float* b_out = (const float*)d_in[4];
    float* out = (float*)d_out;

    dim3 grid(B / 64), block(64);   // 128 blocks x 1 wave: one wave per CU on 128 CUs
    hipLaunchKernelGGL(izh_fused, grid, block, 0, stream,
                       xs, W_in, b_in, W_out, b_out, out);
}

// Round 2
// 636.386 us; speedup vs baseline: 1.0923x; 1.0923x over previous
//
#include <hip/hip_runtime.h>

namespace {

constexpr int T = 2048;
constexpr int B = 8192;
constexpr int D = 32;   // register-ring pipeline depth: 32 dwordx4 in flight/lane

// One Izhikevich Euler step, bit-exact op order vs the JAX reference
// (no FMA contraction, left-associated sums, u-update before spike handling).
__device__ __forceinline__ float izh_step(float& v, float& u, float I) {
#pragma clang fp contract(off)
    float m2 = (0.04f * v) * v;       // (0.04*v)*v
    float s1 = m2 + (5.0f * v);
    float s2 = s1 + 140.0f;
    float s3 = s2 - u;
    float s4 = s3 + I;                // DT=1: v + 1.0*s4 == v + s4
    float vn = v + s4;
    float m4 = 0.2f * vn;             // B_P * v_new
    float s5 = m4 - u;
    float un = u + 0.02f * s5;        // DT*A == 0.02 exactly (1.0*0.02)
    bool  sp = (vn >= 30.0f);
    float z  = sp ? 1.0f : 0.0f;
    v = sp ? -65.0f : vn;             // where(z>0, C, v)
    u = un + z * 8.0f;                // u + z*D (z*8 exact)
    return z;
}

__global__ __launch_bounds__(64, 1) void izh_fused(
    const float* __restrict__ xs,
    const float* __restrict__ W_in, const float* __restrict__ b_in,
    const float* __restrict__ W_out, const float* __restrict__ b_out,
    float* __restrict__ out)
{
#pragma clang fp contract(off)
    const int b = blockIdx.x * 64 + threadIdx.x;   // one thread per batch element

    const float w00 = W_in[0], w01 = W_in[1], w02 = W_in[2], w03 = W_in[3];
    const float w10 = W_in[4], w11 = W_in[5], w12 = W_in[6], w13 = W_in[7];
    const float bi0 = b_in[0], bi1 = b_in[1];
    const float wo0 = W_out[0], wo1 = W_out[1];
    const float bo  = b_out[0];

    // States: v0 = C = -65, u0 = B_P*C = -13 (exact in f32).
    float v0 = -65.0f, u0 = -13.0f;
    float v1 = -65.0f, u1 = -13.0f;
    float vo = -65.0f, uo = -13.0f;

    const float4* xp = reinterpret_cast<const float4*>(xs) + b;  // [T][B] float4
    float* op = out + b;

    // Consume one step's input, run 3 izh neurons, store the output spike.
    auto consume = [&](int t, const float4 x) {
#pragma clang fp contract(off)
        float h0 = (((x.x * w00) + (x.y * w01)) + (x.z * w02)) + (x.w * w03);
        h0 = h0 + bi0;
        float h1 = (((x.x * w10) + (x.y * w11)) + (x.z * w12)) + (x.w * w13);
        h1 = h1 + bi1;
        float z0 = izh_step(v0, u0, h0);
        float z1 = izh_step(v1, u1, h1);
        float y  = ((z0 * wo0) + (z1 * wo1)) + bo;
        float zo = izh_step(vo, uo, y);
        op[(size_t)t * B] = zo;
    };

    // Register ring, depth D. One refill issued per consume at the SAME
    // unrolled slot index -> ring stays in registers, per-register vmcnt
    // tracking means each consume waits only for the oldest load.
    float4 ring[D];
#pragma unroll
    for (int j = 0; j < D; ++j) ring[j] = xp[(size_t)j * B];

    // Main: T/D - 1 iterations; loads run ahead by exactly D steps.
    for (int it = 0; it < T / D - 1; ++it) {
        const int tbase = it * D;
#pragma unroll
        for (int j = 0; j < D; ++j) {
            const float4 x = ring[j];                     // wait oldest only
            ring[j] = xp[(size_t)(tbase + D + j) * B];    // refill D ahead
            consume(tbase + j, x);
        }
    }
    // Epilogue: last D steps, no refills.
    {
        const int tbase = T - D;
#pragma unroll
        for (int j = 0; j < D; ++j) consume(tbase + j, ring[j]);
    }
}

} // namespace

extern "C" void kernel_launch(void* const* d_in, const int* in_sizes, int n_in,
                              void* d_out, int out_size, void* d_ws, size_t ws_size,
                              hipStream_t stream) {
    const float* xs    = (const float*)d_in[0];
    const float* W_in  = (const float*)d_in[1];
    const float* b_in  = (const float*)d_in[2];
    const float* W_out = (const float*)d_in[3];
    const float* b_out = (const float*)d_in[4];
    float* out = (float*)d_out;

    dim3 grid(B / 64), block(64);   // 128 blocks x 1 wave: max independent chains
    hipLaunchKernelGGL(izh_fused, grid, block, 0, stream,
                       xs, W_in, b_in, W_out, b_out, out);
}

// Round 3
// 592.809 us; speedup vs baseline: 1.1726x; 1.0735x over previous
//
#include <hip/hip_runtime.h>

namespace {

constexpr int T = 2048;
constexpr int B = 8192;
constexpr int D = 32;   // register-ring pipeline depth

// Izhikevich Euler step, bit-exact op order vs the JAX reference
// (no FMA contraction, left-associated sums, u-update before spike handling).
// Returns the spike predicate; caller forms z / y as needed.
__device__ __forceinline__ bool izh_core(float& v, float& u, float I) {
#pragma clang fp contract(off)
    float m2 = (0.04f * v) * v;       // (0.04*v)*v
    float s1 = m2 + (5.0f * v);
    float s2 = s1 + 140.0f;
    float s3 = s2 - u;
    float s4 = s3 + I;                // DT=1
    float vn = v + s4;
    float m4 = 0.2f * vn;             // B_P * v_new
    float s5 = m4 - u;
    float un = u + 0.02f * s5;        // DT*A == 0.02
    bool  sp = (vn >= 30.0f);
    v = sp ? -65.0f : vn;             // where(z>0, C, v)
    float d8 = sp ? 8.0f : 0.0f;      // z*D with z in {0,1}: exact incl. +/-0
    u = un + d8;                      // matches reference un + z*8 bitwise
    return sp;
}

__global__ __launch_bounds__(64, 1) void izh_fused(
    const float* __restrict__ xs,
    const float* __restrict__ W_in, const float* __restrict__ b_in,
    const float* __restrict__ W_out, const float* __restrict__ b_out,
    float* __restrict__ out)
{
#pragma clang fp contract(off)
    const int b = blockIdx.x * 64 + threadIdx.x;   // one thread per batch element

    const float w00 = W_in[0], w01 = W_in[1], w02 = W_in[2], w03 = W_in[3];
    const float w10 = W_in[4], w11 = W_in[5], w12 = W_in[6], w13 = W_in[7];
    const float bi0 = b_in[0], bi1 = b_in[1];
    const float wo0 = W_out[0], wo1 = W_out[1];
    const float bo  = b_out[0];

    // y = ((z0*wo0) + (z1*wo1)) + bo for z in {0,1}^2, computed with the
    // reference's exact ops so each of the 4 values is bit-identical.
    const float c00 = ((0.0f * wo0) + (0.0f * wo1)) + bo;
    const float c10 = ((1.0f * wo0) + (0.0f * wo1)) + bo;
    const float c01 = ((0.0f * wo0) + (1.0f * wo1)) + bo;
    const float c11 = ((1.0f * wo0) + (1.0f * wo1)) + bo;

    // States: v0 = C = -65, u0 = B_P*C = -13 (exact in f32).
    float v0 = -65.0f, u0 = -13.0f;   // hidden neuron 0
    float v1 = -65.0f, u1 = -13.0f;   // hidden neuron 1
    float vo = -65.0f, uo = -13.0f;   // output neuron

    const float4* xp = reinterpret_cast<const float4*>(xs) + b;  // [T][B] float4
    float* op = out + b;

    // Hidden step t: linear + 2 izh neurons -> y_t (via bit-exact select).
    auto hidden_step = [&](const float4 x) -> float {
#pragma clang fp contract(off)
        float h0 = (((x.x * w00) + (x.y * w01)) + (x.z * w02)) + (x.w * w03);
        h0 = h0 + bi0;
        float h1 = (((x.x * w10) + (x.y * w11)) + (x.z * w12)) + (x.w * w13);
        h1 = h1 + bi1;
        bool sp0 = izh_core(v0, u0, h0);
        bool sp1 = izh_core(v1, u1, h1);
        float ya = sp0 ? c10 : c00;
        float yb = sp0 ? c11 : c01;
        return sp1 ? yb : ya;
    };
    // Output step t: izh on y_t, store spike. Independent of hidden chain.
    auto output_step = [&](int t, float y) {
#pragma clang fp contract(off)
        bool spo = izh_core(vo, uo, y);
        op[(size_t)t * B] = spo ? 1.0f : 0.0f;
    };

    // Register ring: 32 dwordx4 in flight (proven to survive, VGPR=148 R2).
    float4 ring[D];
#pragma unroll
    for (int j = 0; j < D; ++j) ring[j] = xp[(size_t)j * B];

    float y_pend = 0.0f;   // y from hidden step t-1, pending for output step

    // Outer iter 0 (tbase=0): slot 0 has no output step (t-1 < 0).
#pragma unroll
    for (int j = 0; j < D; ++j) {
        const float4 x = ring[j];
        ring[j] = xp[(size_t)(D + j) * B];
        if (j > 0) output_step(j - 1, y_pend);   // j is unroll-constant
        y_pend = hidden_step(x);
    }
    // Main iters: hidden(t) and output(t-1) are independent chains ->
    // the scheduler interleaves them, halving the serial deps per step.
    for (int it = 1; it < T / D - 1; ++it) {
        const int tbase = it * D;
#pragma unroll
        for (int j = 0; j < D; ++j) {
            const float4 x = ring[j];
            ring[j] = xp[(size_t)(tbase + D + j) * B];
            output_step(tbase + j - 1, y_pend);
            y_pend = hidden_step(x);
        }
    }
    // Last outer iter (tbase = T-D): no refills.
    {
        const int tbase = T - D;
#pragma unroll
        for (int j = 0; j < D; ++j) {
            const float4 x = ring[j];
            output_step(tbase + j - 1, y_pend);
            y_pend = hidden_step(x);
        }
    }
    output_step(T - 1, y_pend);
}

} // namespace

extern "C" void kernel_launch(void* const* d_in, const int* in_sizes, int n_in,
                              void* d_out, int out_size, void* d_ws, size_t ws_size,
                              hipStream_t stream) {
    const float* xs    = (const float*)d_in[0];
    const float* W_in  = (const float*)d_in[1];
    const float* b_in  = (const float*)d_in[2];
    const float* W_out = (const float*)d_in[3];
    const float* b_out = (const float*)d_in[4];
    float* out = (float*)d_out;

    dim3 grid(B / 64), block(64);
    hipLaunchKernelGGL(izh_fused, grid, block, 0, stream,
                       xs, W_in, b_in, W_out, b_out, out);
}

// Round 4
// 437.925 us; speedup vs baseline: 1.5874x; 1.3537x over previous
//
#include <hip/hip_runtime.h>

namespace {

constexpr int T   = 2048;
constexpr int B   = 8192;
constexpr int C   = 16;      // steps per chunk (one barrier per chunk)
constexpr int NCH = T / C;   // 128 chunks

// Barrier WITHOUT vmcnt drain: LDS visibility only (s_waitcnt lgkmcnt(0)).
// __syncthreads() would emit s_waitcnt vmcnt(0) and synchronously drain the
// producers' global prefetch ring at every chunk boundary (m97-style stall).
__device__ __forceinline__ void barrier_nodrain() {
    asm volatile("s_waitcnt lgkmcnt(0)\n\ts_barrier" ::: "memory");
}

// Izhikevich Euler step, bit-exact op order vs the JAX reference
// (no FMA contraction, left-assoc sums; validated absmax==0.0 in R1-R3).
__device__ __forceinline__ bool izh_core(float& v, float& u, float I) {
#pragma clang fp contract(off)
    float m2 = (0.04f * v) * v;
    float s1 = m2 + (5.0f * v);
    float s2 = s1 + 140.0f;
    float s3 = s2 - u;
    float s4 = s3 + I;               // DT=1
    float vn = v + s4;
    float m4 = 0.2f * vn;            // B_P * v_new
    float s5 = m4 - u;
    float un = u + 0.02f * s5;       // DT*A
    bool  sp = (vn >= 30.0f);
    v = sp ? -65.0f : vn;            // where(z>0, C, v)
    float d8 = sp ? 8.0f : 0.0f;     // z*D, exact incl. +/-0
    u = un + d8;
    return sp;
}

// 3-wave pipeline per block: wave0/1 = hidden neurons 0/1 (produce spikes),
// wave2 = output neuron (consumes spikes with one-chunk lag, stores result).
__global__ __launch_bounds__(192, 1) void izh3(
    const float* __restrict__ xs,
    const float* __restrict__ W_in, const float* __restrict__ b_in,
    const float* __restrict__ W_out, const float* __restrict__ b_out,
    float* __restrict__ out)
{
#pragma clang fp contract(off)
    __shared__ float zbuf[2][2][C][64];   // [neuron][parity][step-in-chunk][lane]
    const int lane = threadIdx.x & 63;
    const int wid  = threadIdx.x >> 6;    // wave-uniform role id
    const int b    = blockIdx.x * 64 + lane;

    float v = -65.0f, u = -13.0f;         // v0=C, u0=B_P*C (exact in f32)

    if (wid < 2) {
        // ---- hidden producer for neuron `wid` ----
        const float wa = W_in[wid * 4 + 0], wb = W_in[wid * 4 + 1];
        const float wc = W_in[wid * 4 + 2], wd = W_in[wid * 4 + 3];
        const float bi = b_in[wid];
        const float4* xp = reinterpret_cast<const float4*>(xs) + b;

        // Depth-16 register ring (R2-proven pattern): refill same slot after
        // consume; in flight ~16 steps ~= HBM latency. Survives barriers
        // because barrier_nodrain leaves vmcnt alone.
        float4 ring[C];
#pragma unroll
        for (int j = 0; j < C; ++j) ring[j] = xp[(size_t)j * B];

        for (int k = 0; k < NCH; ++k) {
            // Last chunk refills from chunk 0 (harmless, avoids OOB branch).
            const float4* nxt = xp + (size_t)((k + 1) & (NCH - 1)) * C * B;
            const int p = k & 1;
#pragma unroll
            for (int j = 0; j < C; ++j) {
                const float4 x = ring[j];
                ring[j] = nxt[(size_t)j * B];
                float h = (((x.x * wa) + (x.y * wb)) + (x.z * wc)) + (x.w * wd);
                h = h + bi;
                bool sp = izh_core(v, u, h);
                zbuf[wid][p][j][lane] = sp ? 1.0f : 0.0f;
            }
            barrier_nodrain();
        }
    } else {
        // ---- output consumer (lags producers by one chunk) ----
        const float wo0 = W_out[0], wo1 = W_out[1], bo = b_out[0];
        // y = ((z0*wo0)+(z1*wo1))+bo for z in {0,1}^2 with reference's exact
        // op order -> 4 bit-identical constants, selected per step (R3-proven).
        const float c00 = ((0.0f * wo0) + (0.0f * wo1)) + bo;
        const float c10 = ((1.0f * wo0) + (0.0f * wo1)) + bo;
        const float c01 = ((0.0f * wo0) + (1.0f * wo1)) + bo;
        const float c11 = ((1.0f * wo0) + (1.0f * wo1)) + bo;
        float* op = out + b;

        auto consume = [&](int kk) {
#pragma clang fp contract(off)
            const int p  = kk & 1;
            const int tb = kk * C;
#pragma unroll
            for (int j = 0; j < C; ++j) {
                float sp0 = zbuf[0][p][j][lane];
                float sp1 = zbuf[1][p][j][lane];
                float yt  = (sp1 != 0.0f) ? c11 : c10;
                float yf  = (sp1 != 0.0f) ? c01 : c00;
                float y   = (sp0 != 0.0f) ? yt : yf;
                bool spo  = izh_core(v, u, y);
                op[(size_t)(tb + j) * B] = spo ? 1.0f : 0.0f;
            }
        };

        for (int k = 0; k < NCH; ++k) {
            if (k > 0) consume(k - 1);   // wave-uniform branch
            barrier_nodrain();
        }
        consume(NCH - 1);                // epilogue: last chunk, no barrier
    }
}

} // namespace

extern "C" void kernel_launch(void* const* d_in, const int* in_sizes, int n_in,
                              void* d_out, int out_size, void* d_ws, size_t ws_size,
                              hipStream_t stream) {
    const float* xs    = (const float*)d_in[0];
    const float* W_in  = (const float*)d_in[1];
    const float* b_in  = (const float*)d_in[2];
    const float* W_out = (const float*)d_in[3];
    const float* b_out = (const float*)d_in[4];
    float* out = (float*)d_out;

    dim3 grid(B / 64), block(192);   // 128 blocks x 3 waves (3 SIMDs per CU)
    hipLaunchKernelGGL(izh3, grid, block, 0, stream,
                       xs, W_in, b_in, W_out, b_out, out);
}